// Round 1
// 1099.400 us; speedup vs baseline: 1.3755x; 1.3755x over previous
//
#include <hip/hip_runtime.h>

#define N_NODES 256
#define COND    64
#define E_PAIRS 32640
#define OUTCOLS 65280
#define BATCH   512
#define SLOTS   576    // 9 row-tiles of 64 (big rows padded to 64, then small, then pad)
#define D1      256
#define D2      512
#define D3      1024

// ---------------- kernel 0: sort rows by expert mask into 64-aligned slots ----
__global__ void k0_sort(const float* __restrict__ x, int* __restrict__ meta,
                        int* __restrict__ borig) {
    __shared__ int mask[BATCH];
    __shared__ int bor[SLOTS];
    int t = threadIdx.x;                 // blockDim = 576
    if (t < SLOTS) bor[t] = -1;
    if (t < BATCH) mask[t] = (x[t * COND] > 0.0f) ? 1 : 0;
    __syncthreads();
    if (t == 0) {
        int nbig = 0;
        for (int b = 0; b < BATCH; ++b) nbig += mask[b];
        int S = (nbig + 63) & ~63;       // big slots [0,S), small [S, S+nsmall)
        int ib = 0, is = S;
        for (int b = 0; b < BATCH; ++b) {
            if (mask[b]) bor[ib++] = b; else bor[is++] = b;
        }
        meta[0] = S;
    }
    __syncthreads();
    if (t < SLOTS) borig[t] = bor[t];
}

// ---------------- kernel 1: per-row 3-layer MLP -> hidden h[slot][1024] -------
__global__ __launch_bounds__(256) void k1_mlp(
    const float* __restrict__ x,
    const float* __restrict__ bw0, const float* __restrict__ bb0,
    const float* __restrict__ sw0, const float* __restrict__ sb0,
    const float* __restrict__ bw1, const float* __restrict__ bb1,
    const float* __restrict__ sw1, const float* __restrict__ sb1,
    const float* __restrict__ bw2, const float* __restrict__ bb2,
    const float* __restrict__ sw2, const float* __restrict__ sb2,
    const int* __restrict__ borig, float* __restrict__ hbuf) {
    __shared__ float xs[COND];
    __shared__ float h1[D1];
    __shared__ float h2[D2];
    int s = blockIdx.x, t = threadIdx.x;
    int b = borig[s];
    if (b < 0) {                          // pad slot: zero hidden row
        for (int c = t; c < D3; c += 256) hbuf[s * D3 + c] = 0.0f;
        return;
    }
    bool big = x[b * COND] > 0.0f;
    const float* w0 = big ? bw0 : sw0;  const float* b0 = big ? bb0 : sb0;
    const float* w1 = big ? bw1 : sw1;  const float* b1 = big ? bb1 : sb1;
    const float* w2 = big ? bw2 : sw2;  const float* b2 = big ? bb2 : sb2;
    if (t < COND) xs[t] = x[b * COND + t];
    __syncthreads();
    // layer 0: 64 -> 256
    {
        float acc = 0.f;
        #pragma unroll 8
        for (int k = 0; k < COND; ++k) acc = fmaf(xs[k], w0[k * D1 + t], acc);
        h1[t] = fmaxf(acc + b0[t], 0.f);
    }
    __syncthreads();
    // layer 1: 256 -> 512
    {
        float a0 = 0.f, a1 = 0.f;
        #pragma unroll 4
        for (int k = 0; k < D1; ++k) {
            float hv = h1[k];
            a0 = fmaf(hv, w1[k * D2 + t], a0);
            a1 = fmaf(hv, w1[k * D2 + t + 256], a1);
        }
        h2[t]       = fmaxf(a0 + b1[t], 0.f);
        h2[t + 256] = fmaxf(a1 + b1[t + 256], 0.f);
    }
    __syncthreads();
    // layer 2: 512 -> 1024, write to global
    {
        float a0 = 0.f, a1 = 0.f, a2 = 0.f, a3 = 0.f;
        #pragma unroll 4
        for (int k = 0; k < D2; ++k) {
            float hv = h2[k];
            a0 = fmaf(hv, w2[k * D3 + t], a0);
            a1 = fmaf(hv, w2[k * D3 + t + 256], a1);
            a2 = fmaf(hv, w2[k * D3 + t + 512], a2);
            a3 = fmaf(hv, w2[k * D3 + t + 768], a3);
        }
        hbuf[s * D3 + t]       = fmaxf(a0 + b2[t], 0.f);
        hbuf[s * D3 + t + 256] = fmaxf(a1 + b2[t + 256], 0.f);
        hbuf[s * D3 + t + 512] = fmaxf(a2 + b2[t + 512], 0.f);
        hbuf[s * D3 + t + 768] = fmaxf(a3 + b2[t + 768], 0.f);
    }
}

// ---------------- kernel 2: fp32 DIFFERENCE-GEMM (slots x 32640 e-pairs) ------
// For each e-pair the only consumer of (g0,g1) is the comparison g0>=g1, i.e.
//   h·(w3[:,2e]-w3[:,2e+1]) + (b3[2e]-b3[2e+1]) + (gum0-gum1) >= 0.
// So we GEMM against column DIFFERENCES: N halves 65280 -> 32640 (77 -> 38.6
// GFLOP). The subtraction is folded into LDS staging (load 2 float4 of w3,
// store 1 float4 of diffs); inner loop is the proven 8x4-per-thread structure.
#define BM   64
#define BNW  256   // w3 columns per block (= 128 e-pairs = 128 diff columns)
#define BND  128   // diff columns per block
#define BK   16
__global__ __launch_bounds__(256) void k2_logits(
    const float* __restrict__ hbuf,
    const float* __restrict__ bw3, const float* __restrict__ bb3,
    const float* __restrict__ sw3, const float* __restrict__ sb3,
    const float* __restrict__ gum,
    const int* __restrict__ meta, const int* __restrict__ borig,
    unsigned char* __restrict__ bits) {
    __shared__ float hs[BK][BM + 4];    // transposed h tile, stride 68
    __shared__ float wt[BK][BND + 4];   // w-DIFF tile, stride 132
    int tid = threadIdx.x;
    int by = blockIdx.x;                // row-tile 0..8 (fast index -> L2 reuse of w3)
    int bx = blockIdx.y;                // e-tile   0..254 (128 e-pairs each)
    int r0 = by * BM;
    int cb = bx * BNW;                  // global w3 column base (= 2*e0)
    int S = meta[0];
    bool big = (r0 < S);                // row tiles are expert-uniform (64-aligned split)
    const float* w3 = big ? bw3 : sw3;
    const float* b3 = big ? bb3 : sb3;

    int lm  = tid >> 2;                 // h-load: row 0..63
    int lq  = tid & 3;                  // h-load: k quad
    int wk  = tid >> 4;                 // w-load: k row 0..15
    int wc  = (tid & 15) * 16;          // w-load: w3 col offset (16 cols -> 8 diffs)
    int wd  = (tid & 15) * 8;           // w-store: diff col offset

    int tm = tid >> 5;                  // 0..7 : 8 rows each
    int tn = tid & 31;                  // 0..31: 4 diff cols each

    float acc[8][4];
    #pragma unroll
    for (int i = 0; i < 8; ++i)
        #pragma unroll
        for (int j = 0; j < 4; ++j) acc[i][j] = 0.f;

    for (int k0 = 0; k0 < D3; k0 += BK) {
        float4 hv = *(const float4*)&hbuf[(size_t)(r0 + lm) * D3 + k0 + lq * 4];
        const float* wrow = &w3[(size_t)(k0 + wk) * OUTCOLS + cb + wc];
        float4 wv0 = *(const float4*)&wrow[0];
        float4 wv1 = *(const float4*)&wrow[4];
        float4 wv2 = *(const float4*)&wrow[8];
        float4 wv3 = *(const float4*)&wrow[12];
        __syncthreads();                // previous iter's reads done before overwrite
        hs[lq * 4 + 0][lm] = hv.x;
        hs[lq * 4 + 1][lm] = hv.y;
        hs[lq * 4 + 2][lm] = hv.z;
        hs[lq * 4 + 3][lm] = hv.w;
        float4 d0, d1;
        d0.x = wv0.x - wv0.y;  d0.y = wv0.z - wv0.w;
        d0.z = wv1.x - wv1.y;  d0.w = wv1.z - wv1.w;
        d1.x = wv2.x - wv2.y;  d1.y = wv2.z - wv2.w;
        d1.z = wv3.x - wv3.y;  d1.w = wv3.z - wv3.w;
        *(float4*)&wt[wk][wd]     = d0;
        *(float4*)&wt[wk][wd + 4] = d1;
        __syncthreads();
        #pragma unroll
        for (int kk = 0; kk < BK; ++kk) {
            float4 a0 = *(const float4*)&hs[kk][tm * 8];
            float4 a1 = *(const float4*)&hs[kk][tm * 8 + 4];
            float4 bf = *(const float4*)&wt[kk][tn * 4];
            float am[8] = {a0.x, a0.y, a0.z, a0.w, a1.x, a1.y, a1.z, a1.w};
            float bn[4] = {bf.x, bf.y, bf.z, bf.w};
            #pragma unroll
            for (int i = 0; i < 8; ++i)
                #pragma unroll
                for (int j = 0; j < 4; ++j)
                    acc[i][j] = fmaf(am[i], bn[j], acc[i][j]);
        }
    }

    // epilogue: bias-diff + gumbel-diff, compare, store bit bytes
    float4 bv0 = *(const float4*)&b3[cb + tn * 8];
    float4 bv1 = *(const float4*)&b3[cb + tn * 8 + 4];
    float bd0 = bv0.x - bv0.y;
    float bd1 = bv0.z - bv0.w;
    float bd2 = bv1.x - bv1.y;
    float bd3 = bv1.z - bv1.w;
    int ebase = bx * BND + tn * 4;      // first e-pair of this thread's 4
    #pragma unroll
    for (int i = 0; i < 8; ++i) {
        int slot = r0 + tm * 8 + i;
        int b = borig[slot];
        if (b < 0) continue;            // pad slot
        const float* gp = &gum[(size_t)b * OUTCOLS + (size_t)ebase * 2];
        float4 gv0 = *(const float4*)&gp[0];
        float4 gv1 = *(const float4*)&gp[4];
        uchar4 v;
        v.x = ((acc[i][0] + bd0) + (gv0.x - gv0.y) >= 0.f) ? 1 : 0;
        v.y = ((acc[i][1] + bd1) + (gv0.z - gv0.w) >= 0.f) ? 1 : 0;
        v.z = ((acc[i][2] + bd2) + (gv1.x - gv1.y) >= 0.f) ? 1 : 0;
        v.w = ((acc[i][3] + bd3) + (gv1.z - gv1.w) >= 0.f) ? 1 : 0;
        *(uchar4*)&bits[(size_t)b * E_PAIRS + ebase] = v;
    }
}

// ---------------- kernel 3: tiled bit->fp32 expansion with LDS transpose ------
// Block = (tile-pair p, batch b). 64x64 tile (ti,tj), ti<=tj. Stage contiguous
// 64-byte bit rows into LDS, write BOTH (ti,tj) and mirrored (tj,ti) tiles with
// coalesced float4 row stores (256 B per wave-row).
__global__ __launch_bounds__(256) void k3_expand(
    const unsigned char* __restrict__ bits, float* __restrict__ out) {
    __shared__ unsigned char L[64][68];   // stride 68 bytes (17 dwords, coprime-ish)
    const int ti_tab[10] = {0,0,0,0,1,1,1,2,2,3};
    const int tj_tab[10] = {0,1,2,3,1,2,3,2,3,3};
    int p = blockIdx.x;                   // 0..9
    int b = blockIdx.y;                   // 0..511
    int ti = ti_tab[p], tj = tj_tab[p];
    int t = threadIdx.x;

    // ---- stage bits: row r (i = ti*64+r), 16 bytes per thread ----
    {
        int r = t >> 2;                   // 0..63
        int q = t & 3;                    // 0..3
        int i = ti * 64 + r;
        // e(i,j) = i*(511-i)/2 + j - i - 1  (valid for j > i)
        long base = (long)b * E_PAIRS + (long)i * (511 - i) / 2 - i - 1;
        int j0 = tj * 64 + q * 16;
        #pragma unroll
        for (int k = 0; k < 16; ++k) {
            int j = j0 + k;
            unsigned char v = (j > i) ? bits[base + j] : (unsigned char)0;
            L[r][q * 16 + k] = v;
        }
    }
    __syncthreads();

    int h  = t >> 4;                      // 0..15  (row within group of 16)
    int w4 = (t & 15) * 4;                // col base, float4 granularity

    // ---- direct tile: out[b][ti*64+ii][tj*64 + w4 .. +3] ----
    {
        #pragma unroll
        for (int rr = 0; rr < 4; ++rr) {
            int ii = rr * 16 + h;
            int i_ = ti * 64 + ii;
            float4 v;
            if (ti == tj) {
                int jj;
                jj = w4 + 0; v.x = (jj > ii) ? (float)L[ii][jj] : (jj < ii ? (float)L[jj][ii] : 0.f);
                jj = w4 + 1; v.y = (jj > ii) ? (float)L[ii][jj] : (jj < ii ? (float)L[jj][ii] : 0.f);
                jj = w4 + 2; v.z = (jj > ii) ? (float)L[ii][jj] : (jj < ii ? (float)L[jj][ii] : 0.f);
                jj = w4 + 3; v.w = (jj > ii) ? (float)L[ii][jj] : (jj < ii ? (float)L[jj][ii] : 0.f);
            } else {
                v.x = (float)L[ii][w4 + 0];
                v.y = (float)L[ii][w4 + 1];
                v.z = (float)L[ii][w4 + 2];
                v.w = (float)L[ii][w4 + 3];
            }
            size_t o = (((size_t)b * 256 + i_) * 256) + tj * 64 + w4;
            *(float4*)&out[o] = v;
        }
    }

    // ---- mirrored tile (off-diagonal only): out[b][tj*64+jj][ti*64 + w4 ..] ----
    if (ti != tj) {
        #pragma unroll
        for (int rr = 0; rr < 4; ++rr) {
            int jj = rr * 16 + h;
            int j_ = tj * 64 + jj;
            float4 v;                      // value(i=col, j=row) = L[col_local][jj]
            v.x = (float)L[w4 + 0][jj];
            v.y = (float)L[w4 + 1][jj];
            v.z = (float)L[w4 + 2][jj];
            v.w = (float)L[w4 + 3][jj];
            size_t o = (((size_t)b * 256 + j_) * 256) + ti * 64 + w4;
            *(float4*)&out[o] = v;
        }
    }
}

// -----------------------------------------------------------------------------
extern "C" void kernel_launch(void* const* d_in, const int* in_sizes, int n_in,
                              void* d_out, int out_size, void* d_ws, size_t ws_size,
                              hipStream_t stream) {
    const float* x   = (const float*)d_in[0];
    const float* gum = (const float*)d_in[1];
    const float* bw0 = (const float*)d_in[2];  const float* bb0 = (const float*)d_in[3];
    const float* sw0 = (const float*)d_in[4];  const float* sb0 = (const float*)d_in[5];
    const float* bw1 = (const float*)d_in[6];  const float* bb1 = (const float*)d_in[7];
    const float* sw1 = (const float*)d_in[8];  const float* sb1 = (const float*)d_in[9];
    const float* bw2 = (const float*)d_in[10]; const float* bb2 = (const float*)d_in[11];
    const float* sw2 = (const float*)d_in[12]; const float* sb2 = (const float*)d_in[13];
    const float* bw3 = (const float*)d_in[14]; const float* bb3 = (const float*)d_in[15];
    const float* sw3 = (const float*)d_in[16]; const float* sb3 = (const float*)d_in[17];

    char* ws = (char*)d_ws;
    int*   meta  = (int*)ws;                           // 64 B
    int*   borig = (int*)(ws + 64);                    // 576 ints
    float* hbuf  = (float*)(ws + 4096);                // 576*1024 fp32 = 2.25 MB
    unsigned char* bits = (unsigned char*)(ws + 4096 + (size_t)SLOTS * D3 * 4); // 16.7 MB
    float* out = (float*)d_out;

    k0_sort<<<1, SLOTS, 0, stream>>>(x, meta, borig);
    k1_mlp<<<SLOTS, 256, 0, stream>>>(x, bw0, bb0, sw0, sb0, bw1, bb1, sw1, sb1,
                                      bw2, bb2, sw2, sb2, borig, hbuf);
    k2_logits<<<dim3(9, 255), 256, 0, stream>>>(hbuf, bw3, bb3, sw3, sb3, gum,
                                                meta, borig, bits);
    k3_expand<<<dim3(10, BATCH), 256, 0, stream>>>(bits, out);
}